// Round 2
// baseline (1997.219 us; speedup 1.0000x reference)
//
#include <hip/hip_runtime.h>
#include <hip/hip_bf16.h>
#include <math.h>

// ---- problem constants ----
constexpr int N_    = 4;
constexpr int LQ    = 900;
constexpr int D     = 256;
constexpr int HEADS = 8;
constexpr int DH    = 32;
constexpr int NPTS  = 4;
constexpr int LEN   = 16384;   // 128*128
constexpr int H_    = 128;
constexpr int W_    = 128;
constexpr int DFF   = 1024;
constexpr int NLAYERS = 6;
constexpr int MQ    = N_ * LQ;   // 3600
constexpr int MV    = N_ * LEN;  // 65536

// =====================================================================
// Generic fp32 tiled GEMM: C[M,Nc] = A[M,K] @ B[K,Nc] + bias (+relu, +row-mask-zero)
// 256 threads, thread-tile TM x TN, block-tile BM x BN, K-step BK.
// =====================================================================
template<int BM, int BN, int BK, int TM, int TN, bool RELU, bool MASK>
__global__ __launch_bounds__(256) void gemm_f32(
    const float* __restrict__ A, const float* __restrict__ B,
    const float* __restrict__ bias, float* __restrict__ C,
    int M, int Nc, int K, const unsigned char* __restrict__ mask)
{
    constexpr int TX = BN / TN;           // threads along N
    constexpr int TY = 256 / TX;          // threads along M
    static_assert(TY * TM == BM, "tile geometry");

    __shared__ float As[BK][BM];          // stored transposed: As[k][m]
    __shared__ float Bs[BK][BN];

    const int tid = threadIdx.x;
    const int tx  = tid % TX;
    const int ty  = tid / TX;
    const int row0 = blockIdx.y * BM;
    const int col0 = blockIdx.x * BN;

    float acc[TM][TN];
#pragma unroll
    for (int i = 0; i < TM; ++i)
#pragma unroll
        for (int j = 0; j < TN; ++j) acc[i][j] = 0.f;

    for (int k0 = 0; k0 < K; k0 += BK) {
        // load A tile (BM x BK), store transposed
#pragma unroll
        for (int i = tid; i < BM * BK / 4; i += 256) {
            int r  = i / (BK / 4);
            int c4 = i % (BK / 4);
            int rg = row0 + r;
            float4 v = make_float4(0.f, 0.f, 0.f, 0.f);
            if (rg < M) v = *(const float4*)(A + (size_t)rg * K + k0 + c4 * 4);
            As[c4 * 4 + 0][r] = v.x;
            As[c4 * 4 + 1][r] = v.y;
            As[c4 * 4 + 2][r] = v.z;
            As[c4 * 4 + 3][r] = v.w;
        }
        // load B tile (BK x BN)
#pragma unroll
        for (int i = tid; i < BK * BN / 4; i += 256) {
            int r  = i / (BN / 4);
            int c4 = i % (BN / 4);
            float4 v = *(const float4*)(B + (size_t)(k0 + r) * Nc + col0 + c4 * 4);
            *(float4*)&Bs[r][c4 * 4] = v;
        }
        __syncthreads();

#pragma unroll
        for (int k = 0; k < BK; ++k) {
            float a[TM], b[TN];
#pragma unroll
            for (int i = 0; i < TM; ++i) a[i] = As[k][ty * TM + i];
#pragma unroll
            for (int j = 0; j < TN; ++j) b[j] = Bs[k][tx * TN + j];
#pragma unroll
            for (int i = 0; i < TM; ++i)
#pragma unroll
                for (int j = 0; j < TN; ++j)
                    acc[i][j] = fmaf(a[i], b[j], acc[i][j]);
        }
        __syncthreads();
    }

    // epilogue
#pragma unroll
    for (int i = 0; i < TM; ++i) {
        int r = row0 + ty * TM + i;
        if (r >= M) continue;
        float mz = 1.f;
        if (MASK) mz = mask[r] ? 0.f : 1.f;
#pragma unroll
        for (int j = 0; j < TN; ++j) {
            int c = col0 + tx * TN + j;
            float v = acc[i][j] + bias[c];
            if (RELU) v = fmaxf(v, 0.f);
            C[(size_t)r * Nc + c] = v * mz;
        }
    }
}

// =====================================================================
// q = a + b, vectorized float4. n4 = total/4 (exact multiple).
// =====================================================================
__global__ __launch_bounds__(256) void add_kernel(
    const float* __restrict__ a, const float* __restrict__ b,
    float* __restrict__ c, int n4)
{
    int i = blockIdx.x * 256 + threadIdx.x;
    if (i >= n4) return;
    float4 va = ((const float4*)a)[i];
    float4 vb = ((const float4*)b)[i];
    float4 vo;
    vo.x = va.x + vb.x; vo.y = va.y + vb.y; vo.z = va.z + vb.z; vo.w = va.w + vb.w;
    ((float4*)c)[i] = vo;
}

// =====================================================================
// prep: per (n,q): softmax over 4 attn logits PER HEAD; sampling locations.
// off: (MQ,64) layout h*8+p*2+c ; awl: (MQ,32) layout h*4+p
// loc out: (MQ, 32, 2) ; aw out: (MQ, 32)
// =====================================================================
__global__ __launch_bounds__(256) void prep_kernel(
    const float* __restrict__ off, const float* __restrict__ awl,
    const float* __restrict__ ref_prev, const float* __restrict__ svr,
    float* __restrict__ loc, float* __restrict__ aw)
{
    int idx = blockIdx.x * 256 + threadIdx.x;
    if (idx >= MQ) return;
    int n = idx / LQ;

    float vr0 = svr[n * 2 + 0], vr1 = svr[n * 2 + 1];
    float r0 = ref_prev[idx * 4 + 0] * vr0;
    float r1 = ref_prev[idx * 4 + 1] * vr1;
    float r2 = ref_prev[idx * 4 + 2] * vr0;
    float r3 = ref_prev[idx * 4 + 3] * vr1;

    // softmax over the 4 points WITHIN each head (reference: reshape(...,HEADS,NLEV*NPTS), softmax(-1))
#pragma unroll
    for (int h = 0; h < HEADS; ++h) {
        float l[4];
        float mx = -1e30f;
#pragma unroll
        for (int p = 0; p < 4; ++p) {
            l[p] = awl[(size_t)idx * 32 + h * 4 + p];
            mx = fmaxf(mx, l[p]);
        }
        float s = 0.f;
#pragma unroll
        for (int p = 0; p < 4; ++p) { l[p] = expf(l[p] - mx); s += l[p]; }
        float inv = 1.f / s;
#pragma unroll
        for (int p = 0; p < 4; ++p) aw[(size_t)idx * 32 + h * 4 + p] = l[p] * inv;
    }

#pragma unroll
    for (int h = 0; h < HEADS; ++h) {
#pragma unroll
        for (int p = 0; p < NPTS; ++p) {
            float ox = off[(size_t)idx * 64 + h * 8 + p * 2 + 0];
            float oy = off[(size_t)idx * 64 + h * 8 + p * 2 + 1];
            float lx = r0 + ox * (1.f / NPTS) * r2 * 0.5f;
            float ly = r1 + oy * (1.f / NPTS) * r3 * 0.5f;
            loc[((size_t)idx * 32 + h * 4 + p) * 2 + 0] = lx;
            loc[((size_t)idx * 32 + h * 4 + p) * 2 + 1] = ly;
        }
    }
}

// =====================================================================
// sample: bilinear gather + weighted sum over points.
// value: (N, LEN, D) fp32 (masked, bias-added). attn out: (MQ, D).
// block = 256 threads = 8 heads x 32 dh lanes; one block per (n,q).
// =====================================================================
__global__ __launch_bounds__(256) void sample_kernel(
    const float* __restrict__ value, const float* __restrict__ loc,
    const float* __restrict__ aw, float* __restrict__ attn)
{
    int nq = blockIdx.x;               // 0..MQ-1
    int h  = threadIdx.x >> 5;         // 0..7
    int dh = threadIdx.x & 31;         // 0..31
    int n  = nq / LQ;

    const float* vbase = value + (size_t)n * LEN * D + h * DH + dh;
    float acc = 0.f;

#pragma unroll
    for (int p = 0; p < NPTS; ++p) {
        float lx = loc[((size_t)nq * 32 + h * 4 + p) * 2 + 0];
        float ly = loc[((size_t)nq * 32 + h * 4 + p) * 2 + 1];
        float w  = aw[(size_t)nq * 32 + h * 4 + p];

        float x = lx * W_ - 0.5f;
        float y = ly * H_ - 0.5f;
        // clamp to avoid UB on int cast for crazy values; semantics unchanged
        x = fminf(fmaxf(x, -1e4f), 1e4f);
        y = fminf(fmaxf(y, -1e4f), 1e4f);
        float x0f = floorf(x), y0f = floorf(y);
        float wx = x - x0f, wy = y - y0f;
        int x0 = (int)x0f, y0 = (int)y0f;

        float v00 = 0.f, v10 = 0.f, v01 = 0.f, v11 = 0.f;
        bool xin0 = (x0 >= 0 && x0 < W_);
        bool xin1 = (x0 + 1 >= 0 && x0 + 1 < W_);
        bool yin0 = (y0 >= 0 && y0 < H_);
        bool yin1 = (y0 + 1 >= 0 && y0 + 1 < H_);
        if (xin0 && yin0) v00 = vbase[(size_t)(y0 * W_ + x0) * D];
        if (xin1 && yin0) v10 = vbase[(size_t)(y0 * W_ + x0 + 1) * D];
        if (xin0 && yin1) v01 = vbase[(size_t)((y0 + 1) * W_ + x0) * D];
        if (xin1 && yin1) v11 = vbase[(size_t)((y0 + 1) * W_ + x0 + 1) * D];

        float bil = v00 * (1.f - wx) * (1.f - wy)
                  + v10 * wx * (1.f - wy)
                  + v01 * (1.f - wx) * wy
                  + v11 * wx * wy;
        acc += w * bil;
    }
    attn[(size_t)nq * D + h * DH + dh] = acc;
}

// =====================================================================
// LN over D=256: out = LN(a+b)*g + be.  4 rows per 256-thread block
// (one wave64 per row, 4 elems per lane).
// =====================================================================
__global__ __launch_bounds__(256) void ln_kernel(
    const float* __restrict__ a, const float* __restrict__ b,
    const float* __restrict__ g, const float* __restrict__ be,
    float* __restrict__ out)
{
    int row  = blockIdx.x * 4 + (threadIdx.x >> 6);
    int lane = threadIdx.x & 63;
    if (row >= MQ) return;

    const float4 va = *(const float4*)(a + (size_t)row * D + lane * 4);
    const float4 vb = *(const float4*)(b + (size_t)row * D + lane * 4);
    float x[4] = { va.x + vb.x, va.y + vb.y, va.z + vb.z, va.w + vb.w };

    float s = x[0] + x[1] + x[2] + x[3];
    float s2 = x[0]*x[0] + x[1]*x[1] + x[2]*x[2] + x[3]*x[3];
#pragma unroll
    for (int o = 32; o >= 1; o >>= 1) {
        s  += __shfl_xor(s,  o);
        s2 += __shfl_xor(s2, o);
    }
    float mean = s * (1.f / D);
    float var  = s2 * (1.f / D) - mean * mean;
    float rinv = rsqrtf(var + 1e-5f);

    float4 vg = *(const float4*)(g  + lane * 4);
    float4 vbe = *(const float4*)(be + lane * 4);
    float4 vo;
    vo.x = (x[0] - mean) * rinv * vg.x + vbe.x;
    vo.y = (x[1] - mean) * rinv * vg.y + vbe.y;
    vo.z = (x[2] - mean) * rinv * vg.z + vbe.z;
    vo.w = (x[3] - mean) * rinv * vg.w + vbe.w;
    *(float4*)(out + (size_t)row * D + lane * 4) = vo;
}

// =====================================================================
// bbox final: t3 = t2 @ Wb3 + bb3 (4 cols); ref = sigmoid(t3 + inv_sigmoid(ref_prev))
// one wave64 per row; 4 rows per block.
// =====================================================================
__global__ __launch_bounds__(256) void bbox_kernel(
    const float* __restrict__ t2, const float* __restrict__ Wb3,
    const float* __restrict__ bb3, const float* __restrict__ ref_prev,
    float* __restrict__ ref_out)
{
    int row  = blockIdx.x * 4 + (threadIdx.x >> 6);
    int lane = threadIdx.x & 63;
    if (row >= MQ) return;

    float acc0 = 0.f, acc1 = 0.f, acc2 = 0.f, acc3 = 0.f;
    const float* tp = t2 + (size_t)row * D;
#pragma unroll
    for (int kk = 0; kk < D / 64; ++kk) {
        int k = lane + kk * 64;
        float tv = tp[k];
        const float4 wrow = *(const float4*)(Wb3 + (size_t)k * 4);
        acc0 = fmaf(tv, wrow.x, acc0);
        acc1 = fmaf(tv, wrow.y, acc1);
        acc2 = fmaf(tv, wrow.z, acc2);
        acc3 = fmaf(tv, wrow.w, acc3);
    }
#pragma unroll
    for (int o = 32; o >= 1; o >>= 1) {
        acc0 += __shfl_xor(acc0, o);
        acc1 += __shfl_xor(acc1, o);
        acc2 += __shfl_xor(acc2, o);
        acc3 += __shfl_xor(acc3, o);
    }
    if (lane == 0) {
        float t3[4] = { acc0 + bb3[0], acc1 + bb3[1], acc2 + bb3[2], acc3 + bb3[3] };
#pragma unroll
        for (int c = 0; c < 4; ++c) {
            float rp = ref_prev[(size_t)row * 4 + c];
            float xc = fminf(fmaxf(rp, 0.f), 1.f);
            float invsig = logf(fmaxf(xc, 1e-5f) / fmaxf(1.f - xc, 1e-5f));
            float sarg = t3[c] + invsig;
            ref_out[(size_t)row * 4 + c] = 1.f / (1.f + expf(-sarg));
        }
    }
}

// =====================================================================
// launcher
// =====================================================================
extern "C" void kernel_launch(void* const* d_in, const int* in_sizes, int n_in,
                              void* d_out, int out_size, void* d_ws, size_t ws_size,
                              hipStream_t stream)
{
    const float* tgt    = (const float*)d_in[0];
    const float* refpts = (const float*)d_in[1];
    const float* src    = (const float*)d_in[2];
    const float* svr    = (const float*)d_in[3];
    const float* qpos   = (const float*)d_in[4];
    const float* Wo     = (const float*)d_in[5];
    const float* bo     = (const float*)d_in[6];
    const float* Wa     = (const float*)d_in[7];
    const float* ba     = (const float*)d_in[8];
    const float* Wv     = (const float*)d_in[9];
    const float* bv     = (const float*)d_in[10];
    const float* Wout   = (const float*)d_in[11];
    const float* bout   = (const float*)d_in[12];
    const float* g1     = (const float*)d_in[13];
    const float* b1     = (const float*)d_in[14];
    const float* Wfc    = (const float*)d_in[15];
    const float* bfc    = (const float*)d_in[16];
    const float* Wproj  = (const float*)d_in[17];
    const float* bproj  = (const float*)d_in[18];
    const float* g2     = (const float*)d_in[19];
    const float* b2     = (const float*)d_in[20];
    const float* Wb1    = (const float*)d_in[21];
    const float* bb1    = (const float*)d_in[22];
    const float* Wb2    = (const float*)d_in[23];
    const float* bb2    = (const float*)d_in[24];
    const float* Wb3    = (const float*)d_in[25];
    const float* bb3    = (const float*)d_in[26];
    const unsigned char* mask = (const unsigned char*)d_in[29];

    float* outp  = (float*)d_out;
    float* inter     = outp;                        // (6, N, LQ, D)
    float* inter_ref = outp + (size_t)NLAYERS * MQ * D;  // (6, N, LQ, 4)

    // workspace carve-up (floats)
    float* ws = (float*)d_ws;
    float* value = ws;                 size_t o = (size_t)MV * D;       // 16.7M
    float* qbuf  = ws + o;             o += (size_t)MQ * D;
    float* offb  = ws + o;             o += (size_t)MQ * 64;
    float* awlb  = ws + o;             o += (size_t)MQ * 32;
    float* locb  = ws + o;             o += (size_t)MQ * 32 * 2;
    float* awb   = ws + o;             o += (size_t)MQ * 32;
    float* attnb = ws + o;             o += (size_t)MQ * D;
    float* tmpb  = ws + o;             o += (size_t)MQ * D;
    float* x1b   = ws + o;             o += (size_t)MQ * D;
    float* hmlp  = ws + o;             o += (size_t)MQ * DFF;
    float* t1b   = ws + o;             o += (size_t)MQ * D;
    float* t2b   = ws + o;             o += (size_t)MQ * D;

    for (int l = 0; l < NLAYERS; ++l) {
        const float* out_prev = (l == 0) ? tgt    : inter     + (size_t)(l - 1) * MQ * D;
        const float* ref_prev = (l == 0) ? refpts : inter_ref + (size_t)(l - 1) * MQ * 4;
        float* inter_l     = inter     + (size_t)l * MQ * D;
        float* inter_ref_l = inter_ref + (size_t)l * MQ * 4;

        // 1) value = mask(src @ Wv[l] + bv[l])   (MV x 256)
        gemm_f32<128,128,16,8,8,false,true><<<dim3(D/128, MV/128), 256, 0, stream>>>(
            src, Wv + (size_t)l * D * D, bv + (size_t)l * D, value, MV, D, D, mask);

        // 2) q = output + query_pos
        add_kernel<<<(MQ * D / 4 + 255) / 256, 256, 0, stream>>>(out_prev, qpos, qbuf, MQ * D / 4);

        // 3) off = q @ Wo + bo  (3600 x 64)
        gemm_f32<64,64,16,4,4,false,false><<<dim3(1, (MQ + 63) / 64), 256, 0, stream>>>(
            qbuf, Wo + (size_t)l * D * 64, bo + (size_t)l * 64, offb, MQ, 64, D, nullptr);

        // 4) aw logits = q @ Wa + ba  (3600 x 32)
        gemm_f32<64,32,16,4,2,false,false><<<dim3(1, (MQ + 63) / 64), 256, 0, stream>>>(
            qbuf, Wa + (size_t)l * D * 32, ba + (size_t)l * 32, awlb, MQ, 32, D, nullptr);

        // 5) softmax + sampling locations
        prep_kernel<<<(MQ + 255) / 256, 256, 0, stream>>>(offb, awlb, ref_prev, svr, locb, awb);

        // 6) bilinear sample + point-weighted sum -> attn (3600 x 256)
        sample_kernel<<<MQ, 256, 0, stream>>>(value, locb, awb, attnb);

        // 7) attn @ Wout + bout
        gemm_f32<64,64,16,4,4,false,false><<<dim3(D/64, (MQ + 63) / 64), 256, 0, stream>>>(
            attnb, Wout + (size_t)l * D * D, bout + (size_t)l * D, tmpb, MQ, D, D, nullptr);

        // 8) x1 = LN(out_prev + tmp)
        ln_kernel<<<MQ / 4, 256, 0, stream>>>(out_prev, tmpb, g1 + (size_t)l * D, b1 + (size_t)l * D, x1b);

        // 9) h = relu(x1 @ Wfc + bfc)  (3600 x 1024)
        gemm_f32<64,64,16,4,4,true,false><<<dim3(DFF/64, (MQ + 63) / 64), 256, 0, stream>>>(
            x1b, Wfc + (size_t)l * D * DFF, bfc + (size_t)l * DFF, hmlp, MQ, DFF, D, nullptr);

        // 10) proj: h @ Wproj + bproj
        gemm_f32<64,64,16,4,4,false,false><<<dim3(D/64, (MQ + 63) / 64), 256, 0, stream>>>(
            hmlp, Wproj + (size_t)l * DFF * D, bproj + (size_t)l * D, tmpb, MQ, D, DFF, nullptr);

        // 11) x2 = LN(x1 + tmp) -> written straight into inter[l]
        ln_kernel<<<MQ / 4, 256, 0, stream>>>(x1b, tmpb, g2 + (size_t)l * D, b2 + (size_t)l * D, inter_l);

        // 12) bbox head
        gemm_f32<64,64,16,4,4,true,false><<<dim3(D/64, (MQ + 63) / 64), 256, 0, stream>>>(
            inter_l, Wb1 + (size_t)l * D * D, bb1 + (size_t)l * D, t1b, MQ, D, D, nullptr);
        gemm_f32<64,64,16,4,4,true,false><<<dim3(D/64, (MQ + 63) / 64), 256, 0, stream>>>(
            t1b, Wb2 + (size_t)l * D * D, bb2 + (size_t)l * D, t2b, MQ, D, D, nullptr);
        bbox_kernel<<<MQ / 4, 256, 0, stream>>>(
            t2b, Wb3 + (size_t)l * D * 4, bb3 + (size_t)l * 4, ref_prev, inter_ref_l);
    }
}

// Round 3
// 1475.584 us; speedup vs baseline: 1.3535x; 1.3535x over previous
//
#include <hip/hip_runtime.h>
#include <hip/hip_bf16.h>
#include <math.h>

// ---- problem constants ----
constexpr int N_    = 4;
constexpr int LQ    = 900;
constexpr int D     = 256;
constexpr int HEADS = 8;
constexpr int DH    = 32;
constexpr int NPTS  = 4;
constexpr int LEN   = 16384;   // 128*128
constexpr int H_    = 128;
constexpr int W_    = 128;
constexpr int DFF   = 1024;
constexpr int NLAYERS = 6;
constexpr int MQ    = N_ * LQ;   // 3600
constexpr int MV    = N_ * LEN;  // 65536

typedef __attribute__((ext_vector_type(8))) short bf16x8;
typedef __attribute__((ext_vector_type(4))) float f32x4;

static __device__ __forceinline__ unsigned short f2bf(float v) {
    __hip_bfloat16 h = __float2bfloat16(v);
    return *(unsigned short*)&h;
}
static __device__ __forceinline__ float bf2f(unsigned short u) {
    __hip_bfloat16 h = *(__hip_bfloat16*)&u;
    return __bfloat162float(h);
}

// =====================================================================
// fp32 -> bf16 conversion (contiguous), n8 = count/8
// =====================================================================
__global__ __launch_bounds__(256) void cvt_bf16_kernel(
    const float* __restrict__ in, unsigned short* __restrict__ out, int n8)
{
    int i = blockIdx.x * 256 + threadIdx.x;
    if (i >= n8) return;
    float4 a = ((const float4*)in)[i * 2];
    float4 b = ((const float4*)in)[i * 2 + 1];
    union { bf16x8 v; unsigned short u[8]; } o;
    o.u[0] = f2bf(a.x); o.u[1] = f2bf(a.y); o.u[2] = f2bf(a.z); o.u[3] = f2bf(a.w);
    o.u[4] = f2bf(b.x); o.u[5] = f2bf(b.y); o.u[6] = f2bf(b.z); o.u[7] = f2bf(b.w);
    *(bf16x8*)(out + (size_t)i * 8) = o.v;
}

// =====================================================================
// Wv (NLAYERS,K=256,N=256) fp32 -> WvT (NLAYERS,N,K) bf16 (transpose per layer)
// one thread per output element; coalesced writes along k.
// =====================================================================
__global__ __launch_bounds__(256) void wvt_kernel(
    const float* __restrict__ Wv, unsigned short* __restrict__ WvT)
{
    int i = blockIdx.x * 256 + threadIdx.x;   // flat over NLAYERS*256*256
    if (i >= NLAYERS * D * D) return;
    int k = i & (D - 1);
    int n = (i >> 8) & (D - 1);
    int l = i >> 16;
    WvT[i] = f2bf(Wv[(size_t)l * D * D + (size_t)k * D + n]);
}

// =====================================================================
// MFMA bf16 value GEMM: C[MV,256] = A[MV,256] @ B^T + bias, masked rows -> 0.
// A: src_bf16 row-major [MV][256]; Bt: WvT [256(n)][256(k)] (n-major).
// 128x128 tile, 4 waves (2x2 of 64x64), BK=64, XOR-swizzled LDS.
// Output bf16.
// =====================================================================
__global__ __launch_bounds__(256) void gemm_value_mfma(
    const unsigned short* __restrict__ A, const unsigned short* __restrict__ Bt,
    const float* __restrict__ bias, const unsigned char* __restrict__ mask,
    unsigned short* __restrict__ C)
{
    __shared__ unsigned short Asm[128 * 64];
    __shared__ unsigned short Bsm[128 * 64];

    const int tid  = threadIdx.x;
    const int m0   = blockIdx.y * 128;
    const int n0   = blockIdx.x * 128;
    const int wave = tid >> 6;
    const int lane = tid & 63;
    const int wr   = wave >> 1;      // 0..1 (m)
    const int wc   = wave & 1;       // 0..1 (n)
    const int lg   = lane >> 4;      // 0..3
    const int lr   = lane & 15;      // 0..15

    f32x4 acc[4][4];
#pragma unroll
    for (int i = 0; i < 4; ++i)
#pragma unroll
        for (int j = 0; j < 4; ++j) acc[i][j] = (f32x4){0.f, 0.f, 0.f, 0.f};

    for (int k0 = 0; k0 < D; k0 += 64) {
        // stage A and B tiles: 128 rows x 64 k each, 16B chunks, swizzled
#pragma unroll
        for (int i = 0; i < 4; ++i) {
            int c   = tid + i * 256;        // 0..1023
            int row = c >> 3;               // 0..127
            int kc  = c & 7;                // 0..7 (16B chunk within row)
            int byt = row * 128 + 16 * (kc ^ (row & 7));
            bf16x8 va = *(const bf16x8*)(A  + (size_t)(m0 + row) * D + k0 + kc * 8);
            *(bf16x8*)((char*)Asm + byt) = va;
            bf16x8 vb = *(const bf16x8*)(Bt + (size_t)(n0 + row) * D + k0 + kc * 8);
            *(bf16x8*)((char*)Bsm + byt) = vb;
        }
        __syncthreads();

        bf16x8 af[4][2], bfr[4][2];
#pragma unroll
        for (int i = 0; i < 4; ++i) {
#pragma unroll
            for (int kk = 0; kk < 2; ++kk) {
                int arow = wr * 64 + i * 16 + lr;
                af[i][kk]  = *(const bf16x8*)((char*)Asm + arow * 128 + 16 * ((kk * 4 + lg) ^ (arow & 7)));
                int brow = wc * 64 + i * 16 + lr;
                bfr[i][kk] = *(const bf16x8*)((char*)Bsm + brow * 128 + 16 * ((kk * 4 + lg) ^ (brow & 7)));
            }
        }
#pragma unroll
        for (int kk = 0; kk < 2; ++kk)
#pragma unroll
            for (int i = 0; i < 4; ++i)
#pragma unroll
                for (int j = 0; j < 4; ++j)
                    acc[i][j] = __builtin_amdgcn_mfma_f32_16x16x32_bf16(
                        af[i][kk], bfr[j][kk], acc[i][j], 0, 0, 0);
        __syncthreads();
    }

    // epilogue: C/D layout col = lane&15, row = (lane>>4)*4 + reg  [m89]
#pragma unroll
    for (int i = 0; i < 4; ++i) {
        int mbase = m0 + wr * 64 + i * 16 + lg * 4;
#pragma unroll
        for (int j = 0; j < 4; ++j) {
            int n = n0 + wc * 64 + j * 16 + lr;
            float bn = bias[n];
#pragma unroll
            for (int r = 0; r < 4; ++r) {
                int m = mbase + r;
                float v = acc[i][j][r] + bn;
                if (mask[m]) v = 0.f;
                C[(size_t)m * D + n] = f2bf(v);
            }
        }
    }
}

// =====================================================================
// Generic fp32 tiled GEMM (unchanged, for the small per-query GEMMs)
// =====================================================================
template<int BM, int BN, int BK, int TM, int TN, bool RELU>
__global__ __launch_bounds__(256) void gemm_f32(
    const float* __restrict__ A, const float* __restrict__ B,
    const float* __restrict__ bias, float* __restrict__ C,
    int M, int Nc, int K)
{
    constexpr int TX = BN / TN;
    constexpr int TY = 256 / TX;
    static_assert(TY * TM == BM, "tile geometry");

    __shared__ float As[BK][BM];
    __shared__ float Bs[BK][BN];

    const int tid = threadIdx.x;
    const int tx  = tid % TX;
    const int ty  = tid / TX;
    const int row0 = blockIdx.y * BM;
    const int col0 = blockIdx.x * BN;

    float acc[TM][TN];
#pragma unroll
    for (int i = 0; i < TM; ++i)
#pragma unroll
        for (int j = 0; j < TN; ++j) acc[i][j] = 0.f;

    for (int k0 = 0; k0 < K; k0 += BK) {
#pragma unroll
        for (int i = tid; i < BM * BK / 4; i += 256) {
            int r  = i / (BK / 4);
            int c4 = i % (BK / 4);
            int rg = row0 + r;
            float4 v = make_float4(0.f, 0.f, 0.f, 0.f);
            if (rg < M) v = *(const float4*)(A + (size_t)rg * K + k0 + c4 * 4);
            As[c4 * 4 + 0][r] = v.x;
            As[c4 * 4 + 1][r] = v.y;
            As[c4 * 4 + 2][r] = v.z;
            As[c4 * 4 + 3][r] = v.w;
        }
#pragma unroll
        for (int i = tid; i < BK * BN / 4; i += 256) {
            int r  = i / (BN / 4);
            int c4 = i % (BN / 4);
            float4 v = *(const float4*)(B + (size_t)(k0 + r) * Nc + col0 + c4 * 4);
            *(float4*)&Bs[r][c4 * 4] = v;
        }
        __syncthreads();

#pragma unroll
        for (int k = 0; k < BK; ++k) {
            float a[TM], b[TN];
#pragma unroll
            for (int i = 0; i < TM; ++i) a[i] = As[k][ty * TM + i];
#pragma unroll
            for (int j = 0; j < TN; ++j) b[j] = Bs[k][tx * TN + j];
#pragma unroll
            for (int i = 0; i < TM; ++i)
#pragma unroll
                for (int j = 0; j < TN; ++j)
                    acc[i][j] = fmaf(a[i], b[j], acc[i][j]);
        }
        __syncthreads();
    }

#pragma unroll
    for (int i = 0; i < TM; ++i) {
        int r = row0 + ty * TM + i;
        if (r >= M) continue;
#pragma unroll
        for (int j = 0; j < TN; ++j) {
            int c = col0 + tx * TN + j;
            float v = acc[i][j] + bias[c];
            if (RELU) v = fmaxf(v, 0.f);
            C[(size_t)r * Nc + c] = v;
        }
    }
}

// =====================================================================
// q = a + b
// =====================================================================
__global__ __launch_bounds__(256) void add_kernel(
    const float* __restrict__ a, const float* __restrict__ b,
    float* __restrict__ c, int n4)
{
    int i = blockIdx.x * 256 + threadIdx.x;
    if (i >= n4) return;
    float4 va = ((const float4*)a)[i];
    float4 vb = ((const float4*)b)[i];
    float4 vo;
    vo.x = va.x + vb.x; vo.y = va.y + vb.y; vo.z = va.z + vb.z; vo.w = va.w + vb.w;
    ((float4*)c)[i] = vo;
}

// =====================================================================
// prep: per (n,q): softmax over 4 logits PER HEAD; sampling locations.
// =====================================================================
__global__ __launch_bounds__(256) void prep_kernel(
    const float* __restrict__ off, const float* __restrict__ awl,
    const float* __restrict__ ref_prev, const float* __restrict__ svr,
    float* __restrict__ loc, float* __restrict__ aw)
{
    int idx = blockIdx.x * 256 + threadIdx.x;
    if (idx >= MQ) return;
    int n = idx / LQ;

    float vr0 = svr[n * 2 + 0], vr1 = svr[n * 2 + 1];
    float r0 = ref_prev[idx * 4 + 0] * vr0;
    float r1 = ref_prev[idx * 4 + 1] * vr1;
    float r2 = ref_prev[idx * 4 + 2] * vr0;
    float r3 = ref_prev[idx * 4 + 3] * vr1;

#pragma unroll
    for (int h = 0; h < HEADS; ++h) {
        float l[4];
        float mx = -1e30f;
#pragma unroll
        for (int p = 0; p < 4; ++p) {
            l[p] = awl[(size_t)idx * 32 + h * 4 + p];
            mx = fmaxf(mx, l[p]);
        }
        float s = 0.f;
#pragma unroll
        for (int p = 0; p < 4; ++p) { l[p] = expf(l[p] - mx); s += l[p]; }
        float inv = 1.f / s;
#pragma unroll
        for (int p = 0; p < 4; ++p) aw[(size_t)idx * 32 + h * 4 + p] = l[p] * inv;
    }

#pragma unroll
    for (int h = 0; h < HEADS; ++h) {
#pragma unroll
        for (int p = 0; p < NPTS; ++p) {
            float ox = off[(size_t)idx * 64 + h * 8 + p * 2 + 0];
            float oy = off[(size_t)idx * 64 + h * 8 + p * 2 + 1];
            loc[((size_t)idx * 32 + h * 4 + p) * 2 + 0] = r0 + ox * (1.f / NPTS) * r2 * 0.5f;
            loc[((size_t)idx * 32 + h * 4 + p) * 2 + 1] = r1 + oy * (1.f / NPTS) * r3 * 0.5f;
        }
    }
}

// =====================================================================
// sample: bilinear gather (bf16 value) + weighted sum over points.
// =====================================================================
__global__ __launch_bounds__(256) void sample_kernel(
    const unsigned short* __restrict__ value, const float* __restrict__ loc,
    const float* __restrict__ aw, float* __restrict__ attn)
{
    int nq = blockIdx.x;
    int h  = threadIdx.x >> 5;
    int dh = threadIdx.x & 31;
    int n  = nq / LQ;

    const unsigned short* vbase = value + (size_t)n * LEN * D + h * DH + dh;
    float acc = 0.f;

#pragma unroll
    for (int p = 0; p < NPTS; ++p) {
        float lx = loc[((size_t)nq * 32 + h * 4 + p) * 2 + 0];
        float ly = loc[((size_t)nq * 32 + h * 4 + p) * 2 + 1];
        float w  = aw[(size_t)nq * 32 + h * 4 + p];

        float x = lx * W_ - 0.5f;
        float y = ly * H_ - 0.5f;
        x = fminf(fmaxf(x, -1e4f), 1e4f);
        y = fminf(fmaxf(y, -1e4f), 1e4f);
        float x0f = floorf(x), y0f = floorf(y);
        float wx = x - x0f, wy = y - y0f;
        int x0 = (int)x0f, y0 = (int)y0f;

        float v00 = 0.f, v10 = 0.f, v01 = 0.f, v11 = 0.f;
        bool xin0 = (x0 >= 0 && x0 < W_);
        bool xin1 = (x0 + 1 >= 0 && x0 + 1 < W_);
        bool yin0 = (y0 >= 0 && y0 < H_);
        bool yin1 = (y0 + 1 >= 0 && y0 + 1 < H_);
        if (xin0 && yin0) v00 = bf2f(vbase[(size_t)(y0 * W_ + x0) * D]);
        if (xin1 && yin0) v10 = bf2f(vbase[(size_t)(y0 * W_ + x0 + 1) * D]);
        if (xin0 && yin1) v01 = bf2f(vbase[(size_t)((y0 + 1) * W_ + x0) * D]);
        if (xin1 && yin1) v11 = bf2f(vbase[(size_t)((y0 + 1) * W_ + x0 + 1) * D]);

        float bil = v00 * (1.f - wx) * (1.f - wy)
                  + v10 * wx * (1.f - wy)
                  + v01 * (1.f - wx) * wy
                  + v11 * wx * wy;
        acc += w * bil;
    }
    attn[(size_t)nq * D + h * DH + dh] = acc;
}

// =====================================================================
// LN over D=256: out = LN(a+b)*g + be
// =====================================================================
__global__ __launch_bounds__(256) void ln_kernel(
    const float* __restrict__ a, const float* __restrict__ b,
    const float* __restrict__ g, const float* __restrict__ be,
    float* __restrict__ out)
{
    int row  = blockIdx.x * 4 + (threadIdx.x >> 6);
    int lane = threadIdx.x & 63;
    if (row >= MQ) return;

    const float4 va = *(const float4*)(a + (size_t)row * D + lane * 4);
    const float4 vb = *(const float4*)(b + (size_t)row * D + lane * 4);
    float x[4] = { va.x + vb.x, va.y + vb.y, va.z + vb.z, va.w + vb.w };

    float s = x[0] + x[1] + x[2] + x[3];
    float s2 = x[0]*x[0] + x[1]*x[1] + x[2]*x[2] + x[3]*x[3];
#pragma unroll
    for (int o = 32; o >= 1; o >>= 1) {
        s  += __shfl_xor(s,  o);
        s2 += __shfl_xor(s2, o);
    }
    float mean = s * (1.f / D);
    float var  = s2 * (1.f / D) - mean * mean;
    float rinv = rsqrtf(var + 1e-5f);

    float4 vg = *(const float4*)(g  + lane * 4);
    float4 vbe = *(const float4*)(be + lane * 4);
    float4 vo;
    vo.x = (x[0] - mean) * rinv * vg.x + vbe.x;
    vo.y = (x[1] - mean) * rinv * vg.y + vbe.y;
    vo.z = (x[2] - mean) * rinv * vg.z + vbe.z;
    vo.w = (x[3] - mean) * rinv * vg.w + vbe.w;
    *(float4*)(out + (size_t)row * D + lane * 4) = vo;
}

// =====================================================================
// bbox final
// =====================================================================
__global__ __launch_bounds__(256) void bbox_kernel(
    const float* __restrict__ t2, const float* __restrict__ Wb3,
    const float* __restrict__ bb3, const float* __restrict__ ref_prev,
    float* __restrict__ ref_out)
{
    int row  = blockIdx.x * 4 + (threadIdx.x >> 6);
    int lane = threadIdx.x & 63;
    if (row >= MQ) return;

    float acc0 = 0.f, acc1 = 0.f, acc2 = 0.f, acc3 = 0.f;
    const float* tp = t2 + (size_t)row * D;
#pragma unroll
    for (int kk = 0; kk < D / 64; ++kk) {
        int k = lane + kk * 64;
        float tv = tp[k];
        const float4 wrow = *(const float4*)(Wb3 + (size_t)k * 4);
        acc0 = fmaf(tv, wrow.x, acc0);
        acc1 = fmaf(tv, wrow.y, acc1);
        acc2 = fmaf(tv, wrow.z, acc2);
        acc3 = fmaf(tv, wrow.w, acc3);
    }
#pragma unroll
    for (int o = 32; o >= 1; o >>= 1) {
        acc0 += __shfl_xor(acc0, o);
        acc1 += __shfl_xor(acc1, o);
        acc2 += __shfl_xor(acc2, o);
        acc3 += __shfl_xor(acc3, o);
    }
    if (lane == 0) {
        float t3[4] = { acc0 + bb3[0], acc1 + bb3[1], acc2 + bb3[2], acc3 + bb3[3] };
#pragma unroll
        for (int c = 0; c < 4; ++c) {
            float rp = ref_prev[(size_t)row * 4 + c];
            float xc = fminf(fmaxf(rp, 0.f), 1.f);
            float invsig = logf(fmaxf(xc, 1e-5f) / fmaxf(1.f - xc, 1e-5f));
            float sarg = t3[c] + invsig;
            ref_out[(size_t)row * 4 + c] = 1.f / (1.f + expf(-sarg));
        }
    }
}

// =====================================================================
// launcher
// =====================================================================
extern "C" void kernel_launch(void* const* d_in, const int* in_sizes, int n_in,
                              void* d_out, int out_size, void* d_ws, size_t ws_size,
                              hipStream_t stream)
{
    const float* tgt    = (const float*)d_in[0];
    const float* refpts = (const float*)d_in[1];
    const float* src    = (const float*)d_in[2];
    const float* svr    = (const float*)d_in[3];
    const float* qpos   = (const float*)d_in[4];
    const float* Wo     = (const float*)d_in[5];
    const float* bo     = (const float*)d_in[6];
    const float* Wa     = (const float*)d_in[7];
    const float* ba     = (const float*)d_in[8];
    const float* Wv     = (const float*)d_in[9];
    const float* bv     = (const float*)d_in[10];
    const float* Wout   = (const float*)d_in[11];
    const float* bout   = (const float*)d_in[12];
    const float* g1     = (const float*)d_in[13];
    const float* b1     = (const float*)d_in[14];
    const float* Wfc    = (const float*)d_in[15];
    const float* bfc    = (const float*)d_in[16];
    const float* Wproj  = (const float*)d_in[17];
    const float* bproj  = (const float*)d_in[18];
    const float* g2     = (const float*)d_in[19];
    const float* b2     = (const float*)d_in[20];
    const float* Wb1    = (const float*)d_in[21];
    const float* bb1    = (const float*)d_in[22];
    const float* Wb2    = (const float*)d_in[23];
    const float* bb2    = (const float*)d_in[24];
    const float* Wb3    = (const float*)d_in[25];
    const float* bb3    = (const float*)d_in[26];
    const unsigned char* mask = (const unsigned char*)d_in[29];

    float* outp  = (float*)d_out;
    float* inter     = outp;                             // (6, N, LQ, D)
    float* inter_ref = outp + (size_t)NLAYERS * MQ * D;  // (6, N, LQ, 4)

    // workspace carve-up
    char* wsb = (char*)d_ws;
    unsigned short* value    = (unsigned short*)wsb;  wsb += (size_t)MV * D * 2;          // 33.5 MB
    unsigned short* src_bf16 = (unsigned short*)wsb;  wsb += (size_t)MV * D * 2;          // 33.5 MB
    unsigned short* WvT      = (unsigned short*)wsb;  wsb += (size_t)NLAYERS * D * D * 2; // 0.8 MB
    float* ws = (float*)wsb;
    float* qbuf  = ws;                 size_t o = (size_t)MQ * D;
    float* offb  = ws + o;             o += (size_t)MQ * 64;
    float* awlb  = ws + o;             o += (size_t)MQ * 32;
    float* locb  = ws + o;             o += (size_t)MQ * 32 * 2;
    float* awb   = ws + o;             o += (size_t)MQ * 32;
    float* attnb = ws + o;             o += (size_t)MQ * D;
    float* tmpb  = ws + o;             o += (size_t)MQ * D;
    float* x1b   = ws + o;             o += (size_t)MQ * D;
    float* hmlp  = ws + o;             o += (size_t)MQ * DFF;
    float* t1b   = ws + o;             o += (size_t)MQ * D;
    float* t2b   = ws + o;             o += (size_t)MQ * D;

    // one-time conversions
    cvt_bf16_kernel<<<(MV * D / 8 + 255) / 256, 256, 0, stream>>>(src, src_bf16, MV * D / 8);
    wvt_kernel<<<(NLAYERS * D * D + 255) / 256, 256, 0, stream>>>(Wv, WvT);

    for (int l = 0; l < NLAYERS; ++l) {
        const float* out_prev = (l == 0) ? tgt    : inter     + (size_t)(l - 1) * MQ * D;
        const float* ref_prev = (l == 0) ? refpts : inter_ref + (size_t)(l - 1) * MQ * 4;
        float* inter_l     = inter     + (size_t)l * MQ * D;
        float* inter_ref_l = inter_ref + (size_t)l * MQ * 4;

        // 1) value = mask(src @ Wv[l] + bv[l])  -- bf16 MFMA
        gemm_value_mfma<<<dim3(D / 128, MV / 128), 256, 0, stream>>>(
            src_bf16, WvT + (size_t)l * D * D, bv + (size_t)l * D, mask, value);

        // 2) q = output + query_pos
        add_kernel<<<(MQ * D / 4 + 255) / 256, 256, 0, stream>>>(out_prev, qpos, qbuf, MQ * D / 4);

        // 3) off = q @ Wo + bo  (3600 x 64)
        gemm_f32<64,64,16,4,4,false><<<dim3(1, (MQ + 63) / 64), 256, 0, stream>>>(
            qbuf, Wo + (size_t)l * D * 64, bo + (size_t)l * 64, offb, MQ, 64, D);

        // 4) aw logits = q @ Wa + ba  (3600 x 32)
        gemm_f32<64,32,16,4,2,false><<<dim3(1, (MQ + 63) / 64), 256, 0, stream>>>(
            qbuf, Wa + (size_t)l * D * 32, ba + (size_t)l * 32, awlb, MQ, 32, D);

        // 5) softmax + sampling locations
        prep_kernel<<<(MQ + 255) / 256, 256, 0, stream>>>(offb, awlb, ref_prev, svr, locb, awb);

        // 6) bilinear sample -> attn (3600 x 256)
        sample_kernel<<<MQ, 256, 0, stream>>>(value, locb, awb, attnb);

        // 7) attn @ Wout + bout
        gemm_f32<64,64,16,4,4,false><<<dim3(D/64, (MQ + 63) / 64), 256, 0, stream>>>(
            attnb, Wout + (size_t)l * D * D, bout + (size_t)l * D, tmpb, MQ, D, D);

        // 8) x1 = LN(out_prev + tmp)
        ln_kernel<<<MQ / 4, 256, 0, stream>>>(out_prev, tmpb, g1 + (size_t)l * D, b1 + (size_t)l * D, x1b);

        // 9) h = relu(x1 @ Wfc + bfc)
        gemm_f32<64,64,16,4,4,true><<<dim3(DFF/64, (MQ + 63) / 64), 256, 0, stream>>>(
            x1b, Wfc + (size_t)l * D * DFF, bfc + (size_t)l * DFF, hmlp, MQ, DFF, D);

        // 10) proj
        gemm_f32<64,64,16,4,4,false><<<dim3(D/64, (MQ + 63) / 64), 256, 0, stream>>>(
            hmlp, Wproj + (size_t)l * DFF * D, bproj + (size_t)l * D, tmpb, MQ, D, DFF);

        // 11) x2 = LN(x1 + tmp) -> inter[l]
        ln_kernel<<<MQ / 4, 256, 0, stream>>>(x1b, tmpb, g2 + (size_t)l * D, b2 + (size_t)l * D, inter_l);

        // 12) bbox head
        gemm_f32<64,64,16,4,4,true><<<dim3(D/64, (MQ + 63) / 64), 256, 0, stream>>>(
            inter_l, Wb1 + (size_t)l * D * D, bb1 + (size_t)l * D, t1b, MQ, D, D);
        gemm_f32<64,64,16,4,4,true><<<dim3(D/64, (MQ + 63) / 64), 256, 0, stream>>>(
            t1b, Wb2 + (size_t)l * D * D, bb2 + (size_t)l * D, t2b, MQ, D, D);
        bbox_kernel<<<MQ / 4, 256, 0, stream>>>(
            t2b, Wb3 + (size_t)l * D * 4, bb3 + (size_t)l * 4, ref_prev, inter_ref_l);
    }
}

// Round 4
// 803.351 us; speedup vs baseline: 2.4861x; 1.8368x over previous
//
#include <hip/hip_runtime.h>
#include <hip/hip_bf16.h>
#include <math.h>

// ---- problem constants ----
constexpr int N_    = 4;
constexpr int LQ    = 900;
constexpr int D     = 256;
constexpr int HEADS = 8;
constexpr int DH    = 32;
constexpr int NPTS  = 4;
constexpr int LEN   = 16384;   // 128*128
constexpr int H_    = 128;
constexpr int W_    = 128;
constexpr int DFF   = 1024;
constexpr int NLAYERS = 6;
constexpr int MQ    = N_ * LQ;   // 3600
constexpr int MV    = N_ * LEN;  // 65536
constexpr int MB    = (MQ + 63) / 64;  // 57 row-blocks for query GEMMs

typedef __attribute__((ext_vector_type(8))) short bf16x8;
typedef __attribute__((ext_vector_type(4))) float f32x4;

static __device__ __forceinline__ unsigned short f2bf(float v) {
    __hip_bfloat16 h = __float2bfloat16(v);
    return *(unsigned short*)&h;
}
static __device__ __forceinline__ float bf2f(unsigned short u) {
    __hip_bfloat16 h = *(__hip_bfloat16*)&u;
    return __bfloat162float(h);
}
static __device__ __forceinline__ bf16x8 pack8(const float* a, const float* b4) {
    union { bf16x8 v; unsigned short u[8]; } o;
    o.u[0] = f2bf(a[0]); o.u[1] = f2bf(a[1]); o.u[2] = f2bf(a[2]); o.u[3] = f2bf(a[3]);
    o.u[4] = f2bf(b4[0]); o.u[5] = f2bf(b4[1]); o.u[6] = f2bf(b4[2]); o.u[7] = f2bf(b4[3]);
    return o.v;
}

// =====================================================================
// fp32 -> bf16 conversion (contiguous), n8 = count/8
// =====================================================================
__global__ __launch_bounds__(256) void cvt_bf16_kernel(
    const float* __restrict__ in, unsigned short* __restrict__ out, int n8)
{
    int i = blockIdx.x * 256 + threadIdx.x;
    if (i >= n8) return;
    float4 a = ((const float4*)in)[i * 2];
    float4 b = ((const float4*)in)[i * 2 + 1];
    float af[4] = {a.x, a.y, a.z, a.w}, bff[4] = {b.x, b.y, b.z, b.w};
    *(bf16x8*)(out + (size_t)i * 8) = pack8(af, bff);
}

// =====================================================================
// generic weight transpose+cvt: W (L,K,N) fp32 -> WT (L,Npad,K) bf16, zero pad
// =====================================================================
__global__ __launch_bounds__(256) void wt_cvt_kernel(
    const float* __restrict__ W, unsigned short* __restrict__ WT,
    int K, int Nr, int Npad, int total)
{
    int i = blockIdx.x * 256 + threadIdx.x;
    if (i >= total) return;
    int k = i % K;
    int n = (i / K) % Npad;
    int l = i / (K * Npad);
    WT[i] = (n < Nr) ? f2bf(W[((size_t)l * K + k) * Nr + n]) : (unsigned short)0;
}

// =====================================================================
// WoaT: rows 0..63 = Wo^T (N=64), rows 64..95 = Wa^T (N=32), 96..127 = 0
// =====================================================================
__global__ __launch_bounds__(256) void woat_kernel(
    const float* __restrict__ Wo, const float* __restrict__ Wa,
    unsigned short* __restrict__ WoaT)
{
    int i = blockIdx.x * 256 + threadIdx.x;   // over NLAYERS*128*256
    if (i >= NLAYERS * 128 * D) return;
    int k = i % D;
    int n = (i / D) & 127;
    int l = i / (D * 128);
    float v = 0.f;
    if (n < 64)      v = Wo[((size_t)l * D + k) * 64 + n];
    else if (n < 96) v = Wa[((size_t)l * D + k) * 32 + (n - 64)];
    WoaT[i] = f2bf(v);
}

__global__ __launch_bounds__(256) void bias_concat_kernel(
    const float* __restrict__ bo, const float* __restrict__ ba, float* __restrict__ boa)
{
    int i = blockIdx.x * 256 + threadIdx.x;   // over NLAYERS*128
    if (i >= NLAYERS * 128) return;
    int n = i & 127;
    int l = i >> 7;
    float v = 0.f;
    if (n < 64)      v = bo[l * 64 + n];
    else if (n < 96) v = ba[l * 32 + (n - 64)];
    boa[i] = v;
}

// =====================================================================
// MFMA bf16 value GEMM: C[MV,256] = A @ Bt^T + bias, masked rows -> 0. (validated r3)
// =====================================================================
__global__ __launch_bounds__(256) void gemm_value_mfma(
    const unsigned short* __restrict__ A, const unsigned short* __restrict__ Bt,
    const float* __restrict__ bias, const unsigned char* __restrict__ mask,
    unsigned short* __restrict__ C)
{
    __shared__ unsigned short Asm[128 * 64];
    __shared__ unsigned short Bsm[128 * 64];

    const int tid  = threadIdx.x;
    const int m0   = blockIdx.y * 128;
    const int n0   = blockIdx.x * 128;
    const int wave = tid >> 6;
    const int lane = tid & 63;
    const int wr   = wave >> 1;
    const int wc   = wave & 1;
    const int lg   = lane >> 4;
    const int lr   = lane & 15;

    f32x4 acc[4][4];
#pragma unroll
    for (int i = 0; i < 4; ++i)
#pragma unroll
        for (int j = 0; j < 4; ++j) acc[i][j] = (f32x4){0.f, 0.f, 0.f, 0.f};

    for (int k0 = 0; k0 < D; k0 += 64) {
#pragma unroll
        for (int i = 0; i < 4; ++i) {
            int c   = tid + i * 256;
            int row = c >> 3;
            int kc  = c & 7;
            int byt = row * 128 + 16 * (kc ^ (row & 7));
            bf16x8 va = *(const bf16x8*)(A  + (size_t)(m0 + row) * D + k0 + kc * 8);
            *(bf16x8*)((char*)Asm + byt) = va;
            bf16x8 vb = *(const bf16x8*)(Bt + (size_t)(n0 + row) * D + k0 + kc * 8);
            *(bf16x8*)((char*)Bsm + byt) = vb;
        }
        __syncthreads();

        bf16x8 af[4][2], bfr[4][2];
#pragma unroll
        for (int i = 0; i < 4; ++i) {
#pragma unroll
            for (int kk = 0; kk < 2; ++kk) {
                int arow = wr * 64 + i * 16 + lr;
                af[i][kk]  = *(const bf16x8*)((char*)Asm + arow * 128 + 16 * ((kk * 4 + lg) ^ (arow & 7)));
                int brow = wc * 64 + i * 16 + lr;
                bfr[i][kk] = *(const bf16x8*)((char*)Bsm + brow * 128 + 16 * ((kk * 4 + lg) ^ (brow & 7)));
            }
        }
#pragma unroll
        for (int kk = 0; kk < 2; ++kk)
#pragma unroll
            for (int i = 0; i < 4; ++i)
#pragma unroll
                for (int j = 0; j < 4; ++j)
                    acc[i][j] = __builtin_amdgcn_mfma_f32_16x16x32_bf16(
                        af[i][kk], bfr[j][kk], acc[i][j], 0, 0, 0);
        __syncthreads();
    }

#pragma unroll
    for (int i = 0; i < 4; ++i) {
        int mbase = m0 + wr * 64 + i * 16 + lg * 4;
#pragma unroll
        for (int j = 0; j < 4; ++j) {
            int n = n0 + wc * 64 + j * 16 + lr;
            float bn = bias[n];
#pragma unroll
            for (int r = 0; r < 4; ++r) {
                int m = mbase + r;
                float v = acc[i][j][r] + bn;
                if (mask[m]) v = 0.f;
                C[(size_t)m * D + n] = f2bf(v);
            }
        }
    }
}

// =====================================================================
// MFMA query GEMM: C[M,Nreal] = A[M,K] @ Bt^T + bias (+relu).
// 64x64 tile, 4 waves (2x2 of 32x32), BK=64. A fp32 (cvt on stage, optional
// fused add) or bf16 direct. Output fp32 or bf16, row stride = Nreal.
// Bt has ceil(Nreal/64)*64 rows (zero-padded).
// =====================================================================
template<bool ABF16, bool FUSEADD, bool RELU, bool OUTBF16>
__global__ __launch_bounds__(256) void gemm_q_mfma(
    const void* __restrict__ Av, const float* __restrict__ A2,
    const unsigned short* __restrict__ Bt, const float* __restrict__ bias,
    void* __restrict__ Cv, int M, int Nreal, int K)
{
    __shared__ unsigned short Asm[64 * 64];
    __shared__ unsigned short Bsm[64 * 64];

    const int tid  = threadIdx.x;
    const int m0   = blockIdx.y * 64;
    const int n0   = blockIdx.x * 64;
    const int wave = tid >> 6;
    const int lane = tid & 63;
    const int wr   = wave >> 1;      // 0..1 (m half)
    const int wc   = wave & 1;       // 0..1 (n half)
    const int lg   = lane >> 4;
    const int lr   = lane & 15;

    f32x4 acc[2][2];
#pragma unroll
    for (int i = 0; i < 2; ++i)
#pragma unroll
        for (int j = 0; j < 2; ++j) acc[i][j] = (f32x4){0.f, 0.f, 0.f, 0.f};

    for (int k0 = 0; k0 < K; k0 += 64) {
        // stage A (64 rows x 64 k)
#pragma unroll
        for (int it = 0; it < 2; ++it) {
            int c   = tid + it * 256;       // 0..511
            int row = c >> 3;
            int kc  = c & 7;
            int gm  = m0 + row;
            bf16x8 v = (bf16x8){0,0,0,0,0,0,0,0};
            if (gm < M) {
                if (ABF16) {
                    v = *(const bf16x8*)((const unsigned short*)Av + (size_t)gm * K + k0 + kc * 8);
                } else {
                    const float* ap = (const float*)Av + (size_t)gm * K + k0 + kc * 8;
                    float4 a = *(const float4*)ap;
                    float4 b = *(const float4*)(ap + 4);
                    if (FUSEADD) {
                        const float* qp = A2 + (size_t)gm * K + k0 + kc * 8;
                        float4 qa = *(const float4*)qp;
                        float4 qb = *(const float4*)(qp + 4);
                        a.x += qa.x; a.y += qa.y; a.z += qa.z; a.w += qa.w;
                        b.x += qb.x; b.y += qb.y; b.z += qb.z; b.w += qb.w;
                    }
                    float af_[4] = {a.x, a.y, a.z, a.w}, bf_[4] = {b.x, b.y, b.z, b.w};
                    v = pack8(af_, bf_);
                }
            }
            *(bf16x8*)((char*)Asm + row * 128 + 16 * (kc ^ (row & 7))) = v;
            // stage B (rows always in-bounds: Bt zero-padded to gridDim.x*64 rows)
            bf16x8 vb = *(const bf16x8*)(Bt + (size_t)(n0 + row) * K + k0 + kc * 8);
            *(bf16x8*)((char*)Bsm + row * 128 + 16 * (kc ^ (row & 7))) = vb;
        }
        __syncthreads();

        bf16x8 af[2][2], bfr[2][2];
#pragma unroll
        for (int i = 0; i < 2; ++i) {
#pragma unroll
            for (int kk = 0; kk < 2; ++kk) {
                int arow = wr * 32 + i * 16 + lr;
                af[i][kk]  = *(const bf16x8*)((char*)Asm + arow * 128 + 16 * ((kk * 4 + lg) ^ (arow & 7)));
                int brow = wc * 32 + i * 16 + lr;
                bfr[i][kk] = *(const bf16x8*)((char*)Bsm + brow * 128 + 16 * ((kk * 4 + lg) ^ (brow & 7)));
            }
        }
#pragma unroll
        for (int kk = 0; kk < 2; ++kk)
#pragma unroll
            for (int i = 0; i < 2; ++i)
#pragma unroll
                for (int j = 0; j < 2; ++j)
                    acc[i][j] = __builtin_amdgcn_mfma_f32_16x16x32_bf16(
                        af[i][kk], bfr[j][kk], acc[i][j], 0, 0, 0);
        __syncthreads();
    }

    // epilogue: col = lane&15, row = (lane>>4)*4 + reg  [m89]
#pragma unroll
    for (int i = 0; i < 2; ++i) {
        int mbase = m0 + wr * 32 + i * 16 + lg * 4;
#pragma unroll
        for (int j = 0; j < 2; ++j) {
            int n = n0 + wc * 32 + j * 16 + lr;
            if (n >= Nreal) continue;
            float bn = bias[n];
#pragma unroll
            for (int r = 0; r < 4; ++r) {
                int m = mbase + r;
                if (m >= M) continue;
                float v = acc[i][j][r] + bn;
                if (RELU) v = fmaxf(v, 0.f);
                if (OUTBF16) ((unsigned short*)Cv)[(size_t)m * Nreal + n] = f2bf(v);
                else         ((float*)Cv)[(size_t)m * Nreal + n] = v;
            }
        }
    }
}

// =====================================================================
// prep: per (n,q): softmax over 4 logits PER HEAD; sampling locations.
// qoa: (MQ,96): [0..63] offsets (h*8+p*2+c), [64..95] logits (h*4+p)
// =====================================================================
__global__ __launch_bounds__(256) void prep_kernel(
    const float* __restrict__ qoa,
    const float* __restrict__ ref_prev, const float* __restrict__ svr,
    float* __restrict__ loc, float* __restrict__ aw)
{
    int idx = blockIdx.x * 256 + threadIdx.x;
    if (idx >= MQ) return;
    int n = idx / LQ;

    float vr0 = svr[n * 2 + 0], vr1 = svr[n * 2 + 1];
    float r0 = ref_prev[idx * 4 + 0] * vr0;
    float r1 = ref_prev[idx * 4 + 1] * vr1;
    float r2 = ref_prev[idx * 4 + 2] * vr0;
    float r3 = ref_prev[idx * 4 + 3] * vr1;

    const float* qrow = qoa + (size_t)idx * 96;

#pragma unroll
    for (int h = 0; h < HEADS; ++h) {
        float l[4];
        float mx = -1e30f;
#pragma unroll
        for (int p = 0; p < 4; ++p) {
            l[p] = qrow[64 + h * 4 + p];
            mx = fmaxf(mx, l[p]);
        }
        float s = 0.f;
#pragma unroll
        for (int p = 0; p < 4; ++p) { l[p] = expf(l[p] - mx); s += l[p]; }
        float inv = 1.f / s;
#pragma unroll
        for (int p = 0; p < 4; ++p) aw[(size_t)idx * 32 + h * 4 + p] = l[p] * inv;
    }

#pragma unroll
    for (int h = 0; h < HEADS; ++h) {
#pragma unroll
        for (int p = 0; p < NPTS; ++p) {
            float ox = qrow[h * 8 + p * 2 + 0];
            float oy = qrow[h * 8 + p * 2 + 1];
            loc[((size_t)idx * 32 + h * 4 + p) * 2 + 0] = r0 + ox * (1.f / NPTS) * r2 * 0.5f;
            loc[((size_t)idx * 32 + h * 4 + p) * 2 + 1] = r1 + oy * (1.f / NPTS) * r3 * 0.5f;
        }
    }
}

// =====================================================================
// sample: bilinear gather (bf16 value) + weighted sum over points.
// =====================================================================
__global__ __launch_bounds__(256) void sample_kernel(
    const unsigned short* __restrict__ value, const float* __restrict__ loc,
    const float* __restrict__ aw, float* __restrict__ attn)
{
    int nq = blockIdx.x;
    int h  = threadIdx.x >> 5;
    int dh = threadIdx.x & 31;
    int n  = nq / LQ;

    const unsigned short* vbase = value + (size_t)n * LEN * D + h * DH + dh;
    float acc = 0.f;

#pragma unroll
    for (int p = 0; p < NPTS; ++p) {
        float lx = loc[((size_t)nq * 32 + h * 4 + p) * 2 + 0];
        float ly = loc[((size_t)nq * 32 + h * 4 + p) * 2 + 1];
        float w  = aw[(size_t)nq * 32 + h * 4 + p];

        float x = lx * W_ - 0.5f;
        float y = ly * H_ - 0.5f;
        x = fminf(fmaxf(x, -1e4f), 1e4f);
        y = fminf(fmaxf(y, -1e4f), 1e4f);
        float x0f = floorf(x), y0f = floorf(y);
        float wx = x - x0f, wy = y - y0f;
        int x0 = (int)x0f, y0 = (int)y0f;

        float v00 = 0.f, v10 = 0.f, v01 = 0.f, v11 = 0.f;
        bool xin0 = (x0 >= 0 && x0 < W_);
        bool xin1 = (x0 + 1 >= 0 && x0 + 1 < W_);
        bool yin0 = (y0 >= 0 && y0 < H_);
        bool yin1 = (y0 + 1 >= 0 && y0 + 1 < H_);
        if (xin0 && yin0) v00 = bf2f(vbase[(size_t)(y0 * W_ + x0) * D]);
        if (xin1 && yin0) v10 = bf2f(vbase[(size_t)(y0 * W_ + x0 + 1) * D]);
        if (xin0 && yin1) v01 = bf2f(vbase[(size_t)((y0 + 1) * W_ + x0) * D]);
        if (xin1 && yin1) v11 = bf2f(vbase[(size_t)((y0 + 1) * W_ + x0 + 1) * D]);

        float bil = v00 * (1.f - wx) * (1.f - wy)
                  + v10 * wx * (1.f - wy)
                  + v01 * (1.f - wx) * wy
                  + v11 * wx * wy;
        acc += w * bil;
    }
    attn[(size_t)nq * D + h * DH + dh] = acc;
}

// =====================================================================
// LN over D=256: out = LN(a+b)*g + be
// =====================================================================
__global__ __launch_bounds__(256) void ln_kernel(
    const float* __restrict__ a, const float* __restrict__ b,
    const float* __restrict__ g, const float* __restrict__ be,
    float* __restrict__ out)
{
    int row  = blockIdx.x * 4 + (threadIdx.x >> 6);
    int lane = threadIdx.x & 63;
    if (row >= MQ) return;

    const float4 va = *(const float4*)(a + (size_t)row * D + lane * 4);
    const float4 vb = *(const float4*)(b + (size_t)row * D + lane * 4);
    float x[4] = { va.x + vb.x, va.y + vb.y, va.z + vb.z, va.w + vb.w };

    float s = x[0] + x[1] + x[2] + x[3];
    float s2 = x[0]*x[0] + x[1]*x[1] + x[2]*x[2] + x[3]*x[3];
#pragma unroll
    for (int o = 32; o >= 1; o >>= 1) {
        s  += __shfl_xor(s,  o);
        s2 += __shfl_xor(s2, o);
    }
    float mean = s * (1.f / D);
    float var  = s2 * (1.f / D) - mean * mean;
    float rinv = rsqrtf(var + 1e-5f);

    float4 vg = *(const float4*)(g  + lane * 4);
    float4 vbe = *(const float4*)(be + lane * 4);
    float4 vo;
    vo.x = (x[0] - mean) * rinv * vg.x + vbe.x;
    vo.y = (x[1] - mean) * rinv * vg.y + vbe.y;
    vo.z = (x[2] - mean) * rinv * vg.z + vbe.z;
    vo.w = (x[3] - mean) * rinv * vg.w + vbe.w;
    *(float4*)(out + (size_t)row * D + lane * 4) = vo;
}

// =====================================================================
// bbox final: t3 = t2(bf16) @ Wb3 + bb3; ref = sigmoid(t3 + inv_sigmoid(ref_prev))
// =====================================================================
__global__ __launch_bounds__(256) void bbox_kernel(
    const unsigned short* __restrict__ t2, const float* __restrict__ Wb3,
    const float* __restrict__ bb3, const float* __restrict__ ref_prev,
    float* __restrict__ ref_out)
{
    int row  = blockIdx.x * 4 + (threadIdx.x >> 6);
    int lane = threadIdx.x & 63;
    if (row >= MQ) return;

    float acc0 = 0.f, acc1 = 0.f, acc2 = 0.f, acc3 = 0.f;
    const unsigned short* tp = t2 + (size_t)row * D;
#pragma unroll
    for (int kk = 0; kk < D / 64; ++kk) {
        int k = lane + kk * 64;
        float tv = bf2f(tp[k]);
        const float4 wrow = *(const float4*)(Wb3 + (size_t)k * 4);
        acc0 = fmaf(tv, wrow.x, acc0);
        acc1 = fmaf(tv, wrow.y, acc1);
        acc2 = fmaf(tv, wrow.z, acc2);
        acc3 = fmaf(tv, wrow.w, acc3);
    }
#pragma unroll
    for (int o = 32; o >= 1; o >>= 1) {
        acc0 += __shfl_xor(acc0, o);
        acc1 += __shfl_xor(acc1, o);
        acc2 += __shfl_xor(acc2, o);
        acc3 += __shfl_xor(acc3, o);
    }
    if (lane == 0) {
        float t3[4] = { acc0 + bb3[0], acc1 + bb3[1], acc2 + bb3[2], acc3 + bb3[3] };
#pragma unroll
        for (int c = 0; c < 4; ++c) {
            float rp = ref_prev[(size_t)row * 4 + c];
            float xc = fminf(fmaxf(rp, 0.f), 1.f);
            float invsig = logf(fmaxf(xc, 1e-5f) / fmaxf(1.f - xc, 1e-5f));
            float sarg = t3[c] + invsig;
            ref_out[(size_t)row * 4 + c] = 1.f / (1.f + expf(-sarg));
        }
    }
}

// =====================================================================
// launcher
// =====================================================================
extern "C" void kernel_launch(void* const* d_in, const int* in_sizes, int n_in,
                              void* d_out, int out_size, void* d_ws, size_t ws_size,
                              hipStream_t stream)
{
    const float* tgt    = (const float*)d_in[0];
    const float* refpts = (const float*)d_in[1];
    const float* src    = (const float*)d_in[2];
    const float* svr    = (const float*)d_in[3];
    const float* qpos   = (const float*)d_in[4];
    const float* Wo     = (const float*)d_in[5];
    const float* bo     = (const float*)d_in[6];
    const float* Wa     = (const float*)d_in[7];
    const float* ba     = (const float*)d_in[8];
    const float* Wv     = (const float*)d_in[9];
    const float* bv     = (const float*)d_in[10];
    const float* Wout   = (const float*)d_in[11];
    const float* bout   = (const float*)d_in[12];
    const float* g1     = (const float*)d_in[13];
    const float* b1     = (const float*)d_in[14];
    const float* Wfc    = (const float*)d_in[15];
    const float* bfc    = (const float*)d_in[16];
    const float* Wproj  = (const float*)d_in[17];
    const float* bproj  = (const float*)d_in[18];
    const float* g2     = (const float*)d_in[19];
    const float* b2     = (const float*)d_in[20];
    const float* Wb1    = (const float*)d_in[21];
    const float* bb1    = (const float*)d_in[22];
    const float* Wb2    = (const float*)d_in[23];
    const float* bb2    = (const float*)d_in[24];
    const float* Wb3    = (const float*)d_in[25];
    const float* bb3    = (const float*)d_in[26];
    const unsigned char* mask = (const unsigned char*)d_in[29];

    float* outp  = (float*)d_out;
    float* inter     = outp;                             // (6, N, LQ, D)
    float* inter_ref = outp + (size_t)NLAYERS * MQ * D;  // (6, N, LQ, 4)

    // workspace carve-up
    char* wsb = (char*)d_ws;
    unsigned short* value    = (unsigned short*)wsb;  wsb += (size_t)MV * D * 2;
    unsigned short* src_bf16 = (unsigned short*)wsb;  wsb += (size_t)MV * D * 2;
    unsigned short* WvT      = (unsigned short*)wsb;  wsb += (size_t)NLAYERS * D * D * 2;
    unsigned short* WoaT     = (unsigned short*)wsb;  wsb += (size_t)NLAYERS * 128 * D * 2;
    unsigned short* WoutT    = (unsigned short*)wsb;  wsb += (size_t)NLAYERS * D * D * 2;
    unsigned short* WfcT     = (unsigned short*)wsb;  wsb += (size_t)NLAYERS * DFF * D * 2;
    unsigned short* WprojT   = (unsigned short*)wsb;  wsb += (size_t)NLAYERS * D * DFF * 2;
    unsigned short* Wb1T     = (unsigned short*)wsb;  wsb += (size_t)NLAYERS * D * D * 2;
    unsigned short* Wb2T     = (unsigned short*)wsb;  wsb += (size_t)NLAYERS * D * D * 2;
    unsigned short* hmlp     = (unsigned short*)wsb;  wsb += (size_t)MQ * DFF * 2;
    unsigned short* t1b      = (unsigned short*)wsb;  wsb += (size_t)MQ * D * 2;
    unsigned short* t2b      = (unsigned short*)wsb;  wsb += (size_t)MQ * D * 2;
    float* boa   = (float*)wsb;        wsb += (size_t)NLAYERS * 128 * 4;
    float* ws    = (float*)wsb;
    float* qoab  = ws;                 size_t o = (size_t)MQ * 96;
    float* locb  = ws + o;             o += (size_t)MQ * 32 * 2;
    float* awb   = ws + o;             o += (size_t)MQ * 32;
    float* attnb = ws + o;             o += (size_t)MQ * D;
    float* tmpb  = ws + o;             o += (size_t)MQ * D;
    float* x1b   = ws + o;             o += (size_t)MQ * D;

    // ---- one-time conversions ----
    cvt_bf16_kernel<<<(MV * D / 8 + 255) / 256, 256, 0, stream>>>(src, src_bf16, MV * D / 8);
    {
        int t;
        t = NLAYERS * D * D;
        wt_cvt_kernel<<<(t + 255) / 256, 256, 0, stream>>>(Wv,    WvT,    D,   D,   D,   t);
        wt_cvt_kernel<<<(t + 255) / 256, 256, 0, stream>>>(Wout,  WoutT,  D,   D,   D,   t);
        wt_cvt_kernel<<<(t + 255) / 256, 256, 0, stream>>>(Wb1,   Wb1T,   D,   D,   D,   t);
        wt_cvt_kernel<<<(t + 255) / 256, 256, 0, stream>>>(Wb2,   Wb2T,   D,   D,   D,   t);
        t = NLAYERS * DFF * D;
        wt_cvt_kernel<<<(t + 255) / 256, 256, 0, stream>>>(Wfc,   WfcT,   D,   DFF, DFF, t);
        wt_cvt_kernel<<<(t + 255) / 256, 256, 0, stream>>>(Wproj, WprojT, DFF, D,   D,   t);
        t = NLAYERS * 128 * D;
        woat_kernel<<<(t + 255) / 256, 256, 0, stream>>>(Wo, Wa, WoaT);
        bias_concat_kernel<<<(NLAYERS * 128 + 255) / 256, 256, 0, stream>>>(bo, ba, boa);
    }

    for (int l = 0; l < NLAYERS; ++l) {
        const float* out_prev = (l == 0) ? tgt    : inter     + (size_t)(l - 1) * MQ * D;
        const float* ref_prev = (l == 0) ? refpts : inter_ref + (size_t)(l - 1) * MQ * 4;
        float* inter_l     = inter     + (size_t)l * MQ * D;
        float* inter_ref_l = inter_ref + (size_t)l * MQ * 4;

        // 1) value = mask(src @ Wv[l] + bv[l])
        gemm_value_mfma<<<dim3(D / 128, MV / 128), 256, 0, stream>>>(
            src_bf16, WvT + (size_t)l * D * D, bv + (size_t)l * D, mask, value);

        // 2) qoa = (out_prev + qpos) @ [Wo|Wa] + [bo|ba]   (3600 x 96)
        gemm_q_mfma<false,true,false,false><<<dim3(2, MB), 256, 0, stream>>>(
            out_prev, qpos, WoaT + (size_t)l * 128 * D, boa + (size_t)l * 128,
            qoab, MQ, 96, D);

        // 3) softmax + sampling locations
        prep_kernel<<<(MQ + 255) / 256, 256, 0, stream>>>(qoab, ref_prev, svr, locb, awb);

        // 4) bilinear sample -> attn (3600 x 256)
        sample_kernel<<<MQ, 256, 0, stream>>>(value, locb, awb, attnb);

        // 5) attn @ Wout + bout
        gemm_q_mfma<false,false,false,false><<<dim3(4, MB), 256, 0, stream>>>(
            attnb, nullptr, WoutT + (size_t)l * D * D, bout + (size_t)l * D,
            tmpb, MQ, D, D);

        // 6) x1 = LN(out_prev + tmp)
        ln_kernel<<<MQ / 4, 256, 0, stream>>>(out_prev, tmpb, g1 + (size_t)l * D, b1 + (size_t)l * D, x1b);

        // 7) h = relu(x1 @ Wfc + bfc) -> bf16
        gemm_q_mfma<false,false,true,true><<<dim3(DFF / 64, MB), 256, 0, stream>>>(
            x1b, nullptr, WfcT + (size_t)l * DFF * D, bfc + (size_t)l * DFF,
            hmlp, MQ, DFF, D);

        // 8) proj: h(bf16) @ Wproj + bproj
        gemm_q_mfma<true,false,false,false><<<dim3(4, MB), 256, 0, stream>>>(
            hmlp, nullptr, WprojT + (size_t)l * D * DFF, bproj + (size_t)l * D,
            tmpb, MQ, D, DFF);

        // 9) x2 = LN(x1 + tmp) -> inter[l]
        ln_kernel<<<MQ / 4, 256, 0, stream>>>(x1b, tmpb, g2 + (size_t)l * D, b2 + (size_t)l * D, inter_l);

        // 10) bbox head: t1 = relu(x2 @ Wb1 + bb1) -> bf16
        gemm_q_mfma<false,false,true,true><<<dim3(4, MB), 256, 0, stream>>>(
            inter_l, nullptr, Wb1T + (size_t)l * D * D, bb1 + (size_t)l * D,
            t1b, MQ, D, D);
        // 11) t2 = relu(t1 @ Wb2 + bb2) -> bf16
        gemm_q_mfma<true,false,true,true><<<dim3(4, MB), 256, 0, stream>>>(
            t1b, nullptr, Wb2T + (size_t)l * D * D, bb2 + (size_t)l * D,
            t2b, MQ, D, D);
        // 12) ref refinement
        bbox_kernel<<<MQ / 4, 256, 0, stream>>>(
            t2b, Wb3 + (size_t)l * D * 4, bb3 + (size_t)l * 4, ref_prev, inter_ref_l);
    }
}